// Round 3
// baseline (294.385 us; speedup 1.0000x reference)
//
#include <hip/hip_runtime.h>

// Additive (Bahdanau) attention, fp32 in/out.
// B=2, L=512, S=512, H=8, E=32, D=64.
// scores[b,h,l,s] = sum_e tanh(q[b,l,h,e] + k[b,s,h,e]) * v[e]  (+ masks)
// A = softmax_s(scores); out[b,l,h,d] = sum_s A * values[b,s,h,d]
//
// Key identity: tanh(x) = 1 - 2/(exp2(SC*x)+1), SC = 2*log2(e), and
// exp2(SC*(q+k)) = exp2(SC*q) * exp2(SC*k) -> the exp is hoisted out of the
// (l,s,e) inner loop entirely (eq per-row, ek folded into K staging).
// The "+1" constant term (sum_e v_e) is softmax-shift-invariant -> dropped.
//
// Block = 4 waves = 16 l-rows of one (b,h); wave owns 4 rows (phases 1-2).
// Phase 1: double-buffered LDS K tiles (1 barrier/tile, prefetch hidden under
// compute). Phase 3: PV = (16x512)x(512x64) GEMM via mfma_f32_16x16x32_bf16,
// A fully populated, B (V) streamed from L2 once per block.

#define BB 2
#define LL 512
#define SS 512
#define HH 8
#define EE 32
#define DD 64
#define TS 128          // s-tile per staging buffer
#define SASTR (SS + 8)  // sAb row stride (shorts): 16B-aligned, bank-staggered

typedef __attribute__((ext_vector_type(8))) short bf16x8;
typedef __attribute__((ext_vector_type(4))) float f32x4;

__device__ __forceinline__ short f2bf(float f) {   // fp32 -> bf16, RNE
    unsigned u = __float_as_uint(f);
    u += 0x7FFFu + ((u >> 16) & 1u);
    return (short)(u >> 16);
}

__device__ __forceinline__ float fast_exp2(float x) {
#if __has_builtin(__builtin_amdgcn_exp2f)
    return __builtin_amdgcn_exp2f(x);   // v_exp_f32
#else
    return exp2f(x);
#endif
}
__device__ __forceinline__ float fast_rcp(float x) {
    return __builtin_amdgcn_rcpf(x);    // v_rcp_f32
}

__global__ __launch_bounds__(256, 2) void addattn_kernel(
    const float* __restrict__ q,      // (B,L,H,E)
    const float* __restrict__ k,      // (B,S,H,E)
    const float* __restrict__ vals,   // (B,S,H,D)
    const float* __restrict__ vvec,   // (E)
    const float* __restrict__ mask,   // (L,S)
    const float* __restrict__ klen,   // (B,S)
    float* __restrict__ out)          // (B,L,H,D)
{
    // ek tiles = exp2(SC*k), float4 over e, XOR-swizzled on s (conflict-free
    // phase-1 reads), double-buffered.
    __shared__ float4 sk[2][EE / 4][TS];          // 32 KB
    __shared__ short  sAb[16][SASTR];             // bf16 probs, 16.25 KB
    __shared__ float  sq[16][EE];                 // exp2(SC*q), 2 KB

    const int tid  = threadIdx.x;
    const int w    = tid >> 6;         // wave 0..3
    const int lane = tid & 63;
    const int bh   = blockIdx.x >> 5;  // 16 (b,h) pairs
    const int lblk = blockIdx.x & 31;  // 32 l-blocks of 16 rows
    const int b    = bh >> 3;
    const int h    = bh & 7;
    const int l0   = lblk * 16;

    const float SC = 2.885390081777927f;  // 2*log2(e)

    // ---- stage sq = exp2(SC*q) for this block's 16 rows (2 elems/thread) ----
    {
        int idx = tid * 2;
        int row = idx >> 5;            // 0..15
        int e   = idx & 31;
        float2 t = *(const float2*)(q + (((size_t)b * LL + l0 + row) * HH + h) * EE + e);
        sq[row][e]     = fast_exp2(SC * t.x);
        sq[row][e + 1] = fast_exp2(SC * t.y);
    }

    // ---- stage K tile 0 (buffer 0) ----
    const float4* krow = (const float4*)(k + ((size_t)b * SS * HH + h) * EE);
    {
        #pragma unroll
        for (int i = 0; i < 4; i++) {
            int idx = tid + i * 256;
            int ss  = idx >> 3;        // 0..127
            int e4  = idx & 7;         // coalesced over consecutive threads
            float4 kv = krow[(size_t)ss * (HH * EE / 4) + e4];
            float4 ev = make_float4(fast_exp2(SC * kv.x), fast_exp2(SC * kv.y),
                                    fast_exp2(SC * kv.z), fast_exp2(SC * kv.w));
            sk[0][e4][ss ^ e4] = ev;
        }
    }

    // v2 = -2*v (the +sum(v) shift cancels in softmax)
    float4 v2[EE / 4];
    {
        const float4* vr = (const float4*)vvec;
        #pragma unroll
        for (int i = 0; i < EE / 4; i++) {
            float4 t = vr[i];
            v2[i] = make_float4(-2.f * t.x, -2.f * t.y, -2.f * t.z, -2.f * t.w);
        }
    }

    __syncthreads();

    // eq = exp2(SC*q) for this wave's 4 rows (lane-uniform LDS broadcast)
    float4 eq[4][EE / 4];
    #pragma unroll
    for (int r = 0; r < 4; r++)
        #pragma unroll
        for (int e4 = 0; e4 < EE / 4; e4++)
            eq[r][e4] = *(const float4*)&sq[4 * w + r][e4 * 4];

    // ---- Phase 1: scores. Lane owns s = lane + j*64 within tile. ----
    float sc[4][SS / 64];

    for (int t = 0; t < SS / TS; t++) {
        // prefetch next tile's K into registers (latency hidden by compute)
        float4 kreg[4];
        if (t < SS / TS - 1) {
            #pragma unroll
            for (int i = 0; i < 4; i++) {
                int idx = tid + i * 256;
                int ss  = idx >> 3;
                int e4  = idx & 7;
                kreg[i] = krow[(size_t)((t + 1) * TS + ss) * (HH * EE / 4) + e4];
            }
        }
        const int buf = t & 1;
        #pragma unroll
        for (int j = 0; j < 2; j++) {
            int ssl = lane + j * 64;
            float a0 = 0.f, a1 = 0.f, a2 = 0.f, a3 = 0.f;
            #pragma unroll
            for (int e4 = 0; e4 < EE / 4; e4++) {
                float4 kv = sk[buf][e4][ssl ^ e4];  // conflict-free ds_read_b128
                float4 vv = v2[e4];
                #define TERM(c)                                           \
                {                                                         \
                    float p0 = __builtin_fmaf(eq[0][e4].c, kv.c, 1.f);    \
                    float p1 = __builtin_fmaf(eq[1][e4].c, kv.c, 1.f);    \
                    float p2 = __builtin_fmaf(eq[2][e4].c, kv.c, 1.f);    \
                    float p3 = __builtin_fmaf(eq[3][e4].c, kv.c, 1.f);    \
                    a0 = __builtin_fmaf(vv.c, fast_rcp(p0), a0);          \
                    a1 = __builtin_fmaf(vv.c, fast_rcp(p1), a1);          \
                    a2 = __builtin_fmaf(vv.c, fast_rcp(p2), a2);          \
                    a3 = __builtin_fmaf(vv.c, fast_rcp(p3), a3);          \
                }
                TERM(x) TERM(y) TERM(z) TERM(w)
                #undef TERM
            }
            sc[0][t * 2 + j] = a0;
            sc[1][t * 2 + j] = a1;
            sc[2][t * 2 + j] = a2;
            sc[3][t * 2 + j] = a3;
        }
        if (t < SS / TS - 1) {
            #pragma unroll
            for (int i = 0; i < 4; i++) {
                int idx = tid + i * 256;
                int ss  = idx >> 3;
                int e4  = idx & 7;
                float4 kv = kreg[i];
                float4 ev = make_float4(fast_exp2(SC * kv.x), fast_exp2(SC * kv.y),
                                        fast_exp2(SC * kv.z), fast_exp2(SC * kv.w));
                sk[buf ^ 1][e4][ss ^ e4] = ev;
            }
        }
        __syncthreads();   // one barrier per tile: writes to buf^1, reads from buf
    }

    // ---- Phase 2: masks + per-row softmax, probs -> LDS as bf16. ----
    {
        const float* kl = klen + (size_t)b * SS;
        float klv[SS / 64];
        #pragma unroll
        for (int i = 0; i < SS / 64; i++) klv[i] = kl[lane + i * 64];

        #pragma unroll
        for (int r = 0; r < 4; r++) {
            const float* mrow = mask + (size_t)(l0 + 4 * w + r) * SS;
            float mx = -1e30f;
            #pragma unroll
            for (int i = 0; i < SS / 64; i++) {
                sc[r][i] += mrow[lane + i * 64] + klv[i];
                mx = fmaxf(mx, sc[r][i]);
            }
            #pragma unroll
            for (int off = 1; off < 64; off <<= 1) mx = fmaxf(mx, __shfl_xor(mx, off, 64));
            float ssum = 0.f;
            #pragma unroll
            for (int i = 0; i < SS / 64; i++) {
                sc[r][i] = __expf(sc[r][i] - mx);
                ssum += sc[r][i];
            }
            #pragma unroll
            for (int off = 1; off < 64; off <<= 1) ssum += __shfl_xor(ssum, off, 64);
            float inv = fast_rcp(ssum);
            #pragma unroll
            for (int i = 0; i < SS / 64; i++)
                sAb[4 * w + r][lane + i * 64] = f2bf(sc[r][i] * inv);
        }
    }
    __syncthreads();

    // ---- Phase 3: PV via MFMA. Full (16x512)x(512x64); wave w owns d-chunk.
    // A-frag: A[m=lane&15][kk=quad*8+j]; B-frag: B[kk][n] = V[s=kk][d=w*16+n].
    const int am  = lane & 15;
    const int qd  = lane >> 4;
    const int dof = w * 16 + am;
    const float* vbase = vals + (((size_t)b * SS * HH + h) * DD) + dof;
    f32x4 acc = {0.f, 0.f, 0.f, 0.f};
    #pragma unroll 4
    for (int c = 0; c < SS / 32; c++) {
        int s0 = c * 32 + qd * 8;
        bf16x8 af = *(const bf16x8*)&sAb[am][s0];
        bf16x8 bv;
        #pragma unroll
        for (int j = 0; j < 8; j++)
            bv[j] = f2bf(vbase[(size_t)(s0 + j) * (HH * DD)]);
        acc = __builtin_amdgcn_mfma_f32_16x16x32_bf16(af, bv, acc, 0, 0, 0);
    }
    // C layout: col = lane&15 (d), row = qd*4 + reg  ->  l = l0 + qd*4 + reg
    float* orow = out + (((size_t)b * LL + l0 + qd * 4) * HH + h) * DD + dof;
    #pragma unroll
    for (int r = 0; r < 4; r++)
        orow[(size_t)r * (HH * DD)] = acc[r];
}

extern "C" void kernel_launch(void* const* d_in, const int* in_sizes, int n_in,
                              void* d_out, int out_size, void* d_ws, size_t ws_size,
                              hipStream_t stream) {
    const float* q    = (const float*)d_in[0];  // (B,L,H,E)
    const float* k    = (const float*)d_in[1];  // (B,S,H,E)
    const float* vals = (const float*)d_in[2];  // (B,S,H,D)
    const float* vvec = (const float*)d_in[3];  // (E)
    const float* mask = (const float*)d_in[4];  // (L,S)
    const float* klen = (const float*)d_in[5];  // (B,S)
    float* outp = (float*)d_out;                // (B,L,H,D)

    dim3 grid(BB * HH * (LL / 16));  // 512 blocks: 16 l-rows per block
    dim3 block(256);
    addattn_kernel<<<grid, block, 0, stream>>>(q, k, vals, vvec, mask, klen, outp);
}

// Round 4
// 150.647 us; speedup vs baseline: 1.9541x; 1.9541x over previous
//
#include <hip/hip_runtime.h>

// Additive (Bahdanau) attention, fp32 in/out.
// B=2, L=512, S=512, H=8, E=32, D=64.
// scores[b,h,l,s] = sum_e tanh(q[b,l,h,e] + k[b,s,h,e]) * v[e]  (+ masks)
// A = softmax_s(scores); out[b,l,h,d] = sum_s A * values[b,s,h,d]
//
// tanh(x) = 1 - 2/(exp2(SC*x)+1), SC = 2*log2(e);
// exp2(SC*(q+k)) = exp2(SC*q)*exp2(SC*k) -> exp hoisted out of the (l,s,e)
// inner loop (eq per-row registers, ek folded into K staging). The constant
// sum_e v_e is softmax-shift-invariant -> dropped. Inner loop per element:
// fma + rcp + fma  (1 transcendental, 2 VALU).
//
// R3 lesson: eq for 4 rows (128 VGPRs) spilled catastrophically (391 MB
// scratch writes). This version: 2 rows/wave = 64 VGPRs for eq, ~145 live
// total, no launch_bounds min-waves clamp, no register prefetch.
//
// Block = 4 waves = 8 l-rows of one (b,h); wave owns 2 rows (phases 1-2).
// Phase 3: PV = (8x512)x(512x64) GEMM via mfma_f32_16x16x32_bf16 (A rows
// 8..15 zero), V streamed from L2 once per block.

#define BB 2
#define LL 512
#define SS 512
#define HH 8
#define EE 32
#define DD 64
#define TS 256          // s-tile staged in LDS (single buffer, 2 tiles)
#define SASTR (SS + 8)  // sAb row stride (shorts): 16B-aligned, bank-staggered

typedef __attribute__((ext_vector_type(8))) short bf16x8;
typedef __attribute__((ext_vector_type(4))) float f32x4;

__device__ __forceinline__ short f2bf(float f) {   // fp32 -> bf16, RNE
    unsigned u = __float_as_uint(f);
    u += 0x7FFFu + ((u >> 16) & 1u);
    return (short)(u >> 16);
}

__device__ __forceinline__ float fast_exp2(float x) {
#if __has_builtin(__builtin_amdgcn_exp2f)
    return __builtin_amdgcn_exp2f(x);   // v_exp_f32
#else
    return exp2f(x);
#endif
}
__device__ __forceinline__ float fast_rcp(float x) {
    return __builtin_amdgcn_rcpf(x);    // v_rcp_f32
}

__global__ __launch_bounds__(256) void addattn_kernel(
    const float* __restrict__ q,      // (B,L,H,E)
    const float* __restrict__ k,      // (B,S,H,E)
    const float* __restrict__ vals,   // (B,S,H,D)
    const float* __restrict__ vvec,   // (E)
    const float* __restrict__ mask,   // (L,S)
    const float* __restrict__ klen,   // (B,S)
    float* __restrict__ out)          // (B,L,H,D)
{
    // ek tile = exp2(SC*k), float4 over e, XOR-swizzled on s so the phase-1
    // read (fixed e4, lanes = different s) is conflict-free.
    __shared__ float4 sk[EE / 4][TS];   // 32 KB
    __shared__ short  sAb[8][SASTR];    // bf16 probs, 8.1 KB

    const int tid  = threadIdx.x;
    const int w    = tid >> 6;         // wave 0..3
    const int lane = tid & 63;
    const int bh   = blockIdx.x >> 6;  // 16 (b,h) pairs
    const int lblk = blockIdx.x & 63;  // 64 l-blocks of 8 rows
    const int b    = bh >> 3;
    const int h    = bh & 7;
    const int l0   = lblk * 8;

    const float SC = 2.885390081777927f;  // 2*log2(e)

    // ---- eq = exp2(SC*q) for this wave's 2 rows (wave-uniform loads). ----
    float4 eq[2][EE / 4];
    #pragma unroll
    for (int r = 0; r < 2; r++) {
        const float4* qrow =
            (const float4*)(q + (((size_t)b * LL + l0 + 2 * w + r) * HH + h) * EE);
        #pragma unroll
        for (int e4 = 0; e4 < EE / 4; e4++) {
            float4 t = qrow[e4];
            eq[r][e4] = make_float4(fast_exp2(SC * t.x), fast_exp2(SC * t.y),
                                    fast_exp2(SC * t.z), fast_exp2(SC * t.w));
        }
    }

    // v2 = -2*v (the +sum(v) shift cancels in softmax)
    float4 v2[EE / 4];
    {
        const float4* vr = (const float4*)vvec;
        #pragma unroll
        for (int i = 0; i < EE / 4; i++) {
            float4 t = vr[i];
            v2[i] = make_float4(-2.f * t.x, -2.f * t.y, -2.f * t.z, -2.f * t.w);
        }
    }

    // ---- Phase 1: scores. Lane owns s = lane + j*64 within tile. ----
    float sc[2][SS / 64];
    const float4* krow = (const float4*)(k + ((size_t)b * SS * HH + h) * EE);

    for (int t = 0; t < SS / TS; t++) {
        if (t) __syncthreads();        // protect prior tile's reads
        // cooperative stage: 256 s-rows x 8 float4 = 2048 loads, 8/thread
        #pragma unroll
        for (int i = 0; i < (TS * (EE / 4)) / 256; i++) {
            int idx = tid + i * 256;
            int ss  = idx >> 3;        // 0..255
            int e4  = idx & 7;         // coalesced over consecutive threads
            float4 kv = krow[(size_t)(t * TS + ss) * (HH * EE / 4) + e4];
            float4 ev = make_float4(fast_exp2(SC * kv.x), fast_exp2(SC * kv.y),
                                    fast_exp2(SC * kv.z), fast_exp2(SC * kv.w));
            sk[e4][ss ^ e4] = ev;      // swizzled store
        }
        __syncthreads();

        #pragma unroll
        for (int j = 0; j < TS / 64; j++) {
            int ssl = lane + j * 64;
            float a0 = 0.f, a1 = 0.f;
            #pragma unroll
            for (int e4 = 0; e4 < EE / 4; e4++) {
                float4 kv = sk[e4][ssl ^ e4];  // conflict-free ds_read_b128
                float4 vv = v2[e4];
                #define TERM(c)                                           \
                {                                                         \
                    float p0 = __builtin_fmaf(eq[0][e4].c, kv.c, 1.f);    \
                    float p1 = __builtin_fmaf(eq[1][e4].c, kv.c, 1.f);    \
                    a0 = __builtin_fmaf(vv.c, fast_rcp(p0), a0);          \
                    a1 = __builtin_fmaf(vv.c, fast_rcp(p1), a1);          \
                }
                TERM(x) TERM(y) TERM(z) TERM(w)
                #undef TERM
            }
            sc[0][t * (TS / 64) + j] = a0;
            sc[1][t * (TS / 64) + j] = a1;
        }
    }

    // ---- Phase 2: masks + per-row softmax, probs -> LDS as bf16. ----
    {
        const float* kl = klen + (size_t)b * SS;
        float klv[SS / 64];
        #pragma unroll
        for (int i = 0; i < SS / 64; i++) klv[i] = kl[lane + i * 64];

        #pragma unroll
        for (int r = 0; r < 2; r++) {
            const float* mrow = mask + (size_t)(l0 + 2 * w + r) * SS;
            float mx = -1e30f;
            #pragma unroll
            for (int i = 0; i < SS / 64; i++) {
                sc[r][i] += mrow[lane + i * 64] + klv[i];
                mx = fmaxf(mx, sc[r][i]);
            }
            #pragma unroll
            for (int off = 1; off < 64; off <<= 1) mx = fmaxf(mx, __shfl_xor(mx, off, 64));
            float ssum = 0.f;
            #pragma unroll
            for (int i = 0; i < SS / 64; i++) {
                sc[r][i] = __expf(sc[r][i] - mx);
                ssum += sc[r][i];
            }
            #pragma unroll
            for (int off = 1; off < 64; off <<= 1) ssum += __shfl_xor(ssum, off, 64);
            float inv = fast_rcp(ssum);
            #pragma unroll
            for (int i = 0; i < SS / 64; i++)
                sAb[2 * w + r][lane + i * 64] = f2bf(sc[r][i] * inv);
        }
    }
    __syncthreads();

    // ---- Phase 3: PV via MFMA. (8x512)x(512x64); wave w owns d-chunk.
    // A-frag: A[m=lane&15][kk=quad*8+j], rows m>=8 zero.
    // B-frag: B[kk][n=lane&15] = V[s=kk][d=w*16+n], streamed from L2.
    const int am  = lane & 15;
    const int qd  = lane >> 4;
    const int dof = w * 16 + am;
    const float* vbase = vals + (((size_t)b * SS * HH + h) * DD) + dof;
    f32x4 acc = {0.f, 0.f, 0.f, 0.f};
    #pragma unroll 4
    for (int c = 0; c < SS / 32; c++) {
        int s0 = c * 32 + qd * 8;
        bf16x8 af = {0, 0, 0, 0, 0, 0, 0, 0};
        if (am < 8) af = *(const bf16x8*)&sAb[am][s0];
        bf16x8 bv;
        #pragma unroll
        for (int j = 0; j < 8; j++)
            bv[j] = f2bf(vbase[(size_t)(s0 + j) * (HH * DD)]);
        acc = __builtin_amdgcn_mfma_f32_16x16x32_bf16(af, bv, acc, 0, 0, 0);
    }
    // C layout: col = lane&15 (d), row = qd*4 + reg; valid rows 0..7 -> qd<2
    if (qd < 2) {
        float* orow = out + (((size_t)b * LL + l0 + qd * 4) * HH + h) * DD + dof;
        #pragma unroll
        for (int r = 0; r < 4; r++)
            orow[(size_t)r * (HH * DD)] = acc[r];
    }
}

extern "C" void kernel_launch(void* const* d_in, const int* in_sizes, int n_in,
                              void* d_out, int out_size, void* d_ws, size_t ws_size,
                              hipStream_t stream) {
    const float* q    = (const float*)d_in[0];  // (B,L,H,E)
    const float* k    = (const float*)d_in[1];  // (B,S,H,E)
    const float* vals = (const float*)d_in[2];  // (B,S,H,D)
    const float* vvec = (const float*)d_in[3];  // (E)
    const float* mask = (const float*)d_in[4];  // (L,S)
    const float* klen = (const float*)d_in[5];  // (B,S)
    float* outp = (float*)d_out;                // (B,L,H,D)

    dim3 grid(BB * HH * (LL / 8));   // 1024 blocks: 8 l-rows per block
    dim3 block(256);
    addattn_kernel<<<grid, block, 0, stream>>>(q, k, vals, vvec, mask, klen, outp);
}

// Round 5
// 106.446 us; speedup vs baseline: 2.7656x; 1.4152x over previous
//
#include <hip/hip_runtime.h>

// Additive (Bahdanau) attention, fp32 in/out.
// B=2, L=512, S=512, H=8, E=32, D=64.
// scores[b,h,l,s] = sum_e tanh(q[b,l,h,e] + k[b,s,h,e]) * v[e]  (+ masks)
// A = softmax_s(scores); out[b,l,h,d] = sum_s A * values[b,s,h,d]
//
// tanh(x) = 1 - 2/(exp2(SC*x)+1), SC = 2*log2(e);
// exp2(SC*(q+k)) = exp2(SC*q)*exp2(SC*k): exp hoisted out of the (l,s,e)
// inner loop (eq in registers per row, ek folded into K staging).
// Constant sum_e v_e is softmax-shift-invariant -> dropped.
// Inner loop per element: fma + rcp + fma (1 trans + 2 VALU).
//
// R3 lesson: big per-wave register arrays spill catastrophically.
// R4 lesson: this kernel is latency-hiding (TLP) bound — 16 waves/CU at
// half the VALU work lost to 28 waves/CU at double the VALU work.
// => R5: R2's high-TLP shape (1 row/wave, TS=128, 2048 blocks, low VGPR)
//    plus the halved inner loop, plus 2-stage pipelined phase-3 V loads.

#define BB 2
#define LL 512
#define SS 512
#define HH 8
#define EE 32
#define DD 64
#define TS 128          // s-tile staged in LDS
#define SASTR (SS + 8)  // sAb row stride (shorts): 16B-aligned, bank-staggered

typedef __attribute__((ext_vector_type(8))) short bf16x8;
typedef __attribute__((ext_vector_type(4))) float f32x4;

__device__ __forceinline__ short f2bf(float f) {   // fp32 -> bf16, RNE
    unsigned u = __float_as_uint(f);
    u += 0x7FFFu + ((u >> 16) & 1u);
    return (short)(u >> 16);
}

__device__ __forceinline__ float fast_exp2(float x) {
#if __has_builtin(__builtin_amdgcn_exp2f)
    return __builtin_amdgcn_exp2f(x);   // v_exp_f32
#else
    return exp2f(x);
#endif
}
__device__ __forceinline__ float fast_rcp(float x) {
    return __builtin_amdgcn_rcpf(x);    // v_rcp_f32
}

__global__ __launch_bounds__(256) void addattn_kernel(
    const float* __restrict__ q,      // (B,L,H,E)
    const float* __restrict__ k,      // (B,S,H,E)
    const float* __restrict__ vals,   // (B,S,H,D)
    const float* __restrict__ vvec,   // (E)
    const float* __restrict__ mask,   // (L,S)
    const float* __restrict__ klen,   // (B,S)
    float* __restrict__ out)          // (B,L,H,D)
{
    // ek tile = exp2(SC*k), float4 over e, XOR-swizzled on s so the phase-1
    // read (fixed e4, lanes = different s) is conflict-free.
    __shared__ float4 sk[EE / 4][TS];   // 16 KB
    __shared__ short  sAb[4][SASTR];    // bf16 probs, 4.1 KB

    const int tid  = threadIdx.x;
    const int w    = tid >> 6;         // wave 0..3
    const int lane = tid & 63;
    const int bh   = blockIdx.x >> 7;  // 16 (b,h) pairs
    const int lblk = blockIdx.x & 127; // 128 l-blocks of 4 rows
    const int b    = bh >> 3;
    const int h    = bh & 7;
    const int l    = lblk * 4 + w;     // this wave's row

    const float SC = 2.885390081777927f;  // 2*log2(e)

    // eq = exp2(SC*q) for this wave's row (wave-uniform broadcast loads)
    float4 eq[EE / 4];
    {
        const float4* qrow = (const float4*)(q + (((size_t)b * LL + l) * HH + h) * EE);
        #pragma unroll
        for (int e4 = 0; e4 < EE / 4; e4++) {
            float4 t = qrow[e4];
            eq[e4] = make_float4(fast_exp2(SC * t.x), fast_exp2(SC * t.y),
                                 fast_exp2(SC * t.z), fast_exp2(SC * t.w));
        }
    }
    // v2 = -2*v (the +sum(v) shift cancels in softmax)
    float4 v2[EE / 4];
    {
        const float4* vr = (const float4*)vvec;
        #pragma unroll
        for (int i = 0; i < EE / 4; i++) {
            float4 t = vr[i];
            v2[i] = make_float4(-2.f * t.x, -2.f * t.y, -2.f * t.z, -2.f * t.w);
        }
    }

    // ---- Phase 1: scores. Lane owns s = lane + j*64 within tile. ----
    float sc[SS / 64];
    const float4* krow = (const float4*)(k + ((size_t)b * SS * HH + h) * EE);
    for (int t = 0; t < SS / TS; t++) {
        __syncthreads();
        #pragma unroll
        for (int i = 0; i < (TS * (EE / 4)) / 256; i++) {  // 4 per thread
            int idx = tid + i * 256;
            int ss  = idx >> 3;        // 0..127
            int e4  = idx & 7;         // coalesced over consecutive threads
            float4 kv = krow[(size_t)(t * TS + ss) * (HH * EE / 4) + e4];
            sk[e4][ss ^ e4] = make_float4(
                fast_exp2(SC * kv.x), fast_exp2(SC * kv.y),
                fast_exp2(SC * kv.z), fast_exp2(SC * kv.w));
        }
        __syncthreads();
        #pragma unroll
        for (int j = 0; j < 2; j++) {
            int ssl = lane + j * 64;
            float a0 = 0.f, a1 = 0.f, a2 = 0.f, a3 = 0.f;  // 4 indep chains
            #pragma unroll
            for (int e4 = 0; e4 < EE / 4; e4++) {
                float4 kv = sk[e4][ssl ^ e4];  // conflict-free ds_read_b128
                float4 ev = eq[e4];
                float4 vv = v2[e4];
                a0 = __builtin_fmaf(vv.x, fast_rcp(__builtin_fmaf(ev.x, kv.x, 1.f)), a0);
                a1 = __builtin_fmaf(vv.y, fast_rcp(__builtin_fmaf(ev.y, kv.y, 1.f)), a1);
                a2 = __builtin_fmaf(vv.z, fast_rcp(__builtin_fmaf(ev.z, kv.z, 1.f)), a2);
                a3 = __builtin_fmaf(vv.w, fast_rcp(__builtin_fmaf(ev.w, kv.w, 1.f)), a3);
            }
            sc[t * 2 + j] = (a0 + a1) + (a2 + a3);
        }
    }

    // ---- Phase 2: masks + per-wave softmax, probs -> LDS as bf16. ----
    {
        const float* mrow = mask + (size_t)l * SS;
        const float* kl   = klen + (size_t)b * SS;
        float mx = -1e30f;
        #pragma unroll
        for (int i = 0; i < SS / 64; i++) {
            int s = lane + i * 64;
            sc[i] += mrow[s] + kl[s];
            mx = fmaxf(mx, sc[i]);
        }
        #pragma unroll
        for (int off = 1; off < 64; off <<= 1) mx = fmaxf(mx, __shfl_xor(mx, off, 64));
        float ssum = 0.f;
        #pragma unroll
        for (int i = 0; i < SS / 64; i++) {
            sc[i] = __expf(sc[i] - mx);
            ssum += sc[i];
        }
        #pragma unroll
        for (int off = 1; off < 64; off <<= 1) ssum += __shfl_xor(ssum, off, 64);
        float inv = fast_rcp(ssum);
        #pragma unroll
        for (int i = 0; i < SS / 64; i++)
            sAb[w][lane + i * 64] = f2bf(sc[i] * inv);
    }
    __syncthreads();

    // ---- Phase 3: PV via MFMA, 2-stage pipelined V loads.
    // (4x512)x(512x64); wave w owns d-chunk w*16..w*16+15.
    // A-frag: A[m=lane&15][kk=quad*8+j], rows m>=4 zero.
    // B-frag: B[kk][n=lane&15] = V[s=kk][d=w*16+n], from L2.
    const int am  = lane & 15;
    const int qd  = lane >> 4;
    const int dof = w * 16 + am;
    const float* vbase = vals + (((size_t)b * SS * HH + h) * DD) + dof;
    f32x4 acc = {0.f, 0.f, 0.f, 0.f};
    float vreg[8];
    #pragma unroll
    for (int j = 0; j < 8; j++)
        vreg[j] = vbase[(size_t)(qd * 8 + j) * (HH * DD)];
    for (int c = 0; c < SS / 32; c++) {
        bf16x8 bv;
        #pragma unroll
        for (int j = 0; j < 8; j++) bv[j] = f2bf(vreg[j]);
        if (c < SS / 32 - 1) {
            int s0n = (c + 1) * 32 + qd * 8;
            #pragma unroll
            for (int j = 0; j < 8; j++)
                vreg[j] = vbase[(size_t)(s0n + j) * (HH * DD)];
        }
        bf16x8 af = {0, 0, 0, 0, 0, 0, 0, 0};
        if (am < 4) af = *(const bf16x8*)&sAb[am][c * 32 + qd * 8];
        acc = __builtin_amdgcn_mfma_f32_16x16x32_bf16(af, bv, acc, 0, 0, 0);
    }
    // C layout: col = lane&15 (d), row = qd*4 + reg; valid rows 0..3 -> qd==0
    if (qd == 0) {
        float* orow = out + (((size_t)b * LL + lblk * 4) * HH + h) * DD + dof;
        #pragma unroll
        for (int r = 0; r < 4; r++)
            orow[(size_t)r * (HH * DD)] = acc[r];
    }
}

extern "C" void kernel_launch(void* const* d_in, const int* in_sizes, int n_in,
                              void* d_out, int out_size, void* d_ws, size_t ws_size,
                              hipStream_t stream) {
    const float* q    = (const float*)d_in[0];  // (B,L,H,E)
    const float* k    = (const float*)d_in[1];  // (B,S,H,E)
    const float* vals = (const float*)d_in[2];  // (B,S,H,D)
    const float* vvec = (const float*)d_in[3];  // (E)
    const float* mask = (const float*)d_in[4];  // (L,S)
    const float* klen = (const float*)d_in[5];  // (B,S)
    float* outp = (float*)d_out;                // (B,L,H,D)

    dim3 grid(BB * HH * (LL / 4));   // 2048 blocks: 4 l-rows per block
    dim3 block(256);
    addattn_kernel<<<grid, block, 0, stream>>>(q, k, vals, vvec, mask, klen, outp);
}